// Round 1
// baseline (1129.829 us; speedup 1.0000x reference)
//
#include <hip/hip_runtime.h>

// Problem constants (match reference setup_inputs()).
constexpr int cN1 = 50000;
constexpr int cNL = 3;
constexpr int cN2 = cN1 * cNL;   // 150000
constexpr int cE1 = 800000;
constexpr int cE2 = 2400000;
constexpr int cD  = 64;
#define LEAKY 0.01f

// ---------------------------------------------------------------------------
// Degree accumulation: deg_out[src[e]] += 1, deg_in[dst[e]] += 1
// ---------------------------------------------------------------------------
__global__ void deg_kernel(const int* __restrict__ src, const int* __restrict__ dst,
                           float* __restrict__ dout, float* __restrict__ din, int E) {
    int i = blockIdx.x * blockDim.x + threadIdx.x;
    int stride = gridDim.x * blockDim.x;
    for (; i < E; i += stride) {
        unsafeAtomicAdd(&dout[src[i]], 1.0f);
        unsafeAtomicAdd(&din[dst[i]], 1.0f);
    }
}

// In-place deg -> rsqrt(clamp(deg,1))
__global__ void norm_kernel(float* __restrict__ p, int n) {
    int i = blockIdx.x * blockDim.x + threadIdx.x;
    int stride = gridDim.x * blockDim.x;
    for (; i < n; i += stride) {
        float d = p[i];
        d = d < 1.0f ? 1.0f : d;
        p[i] = rsqrtf(d);
    }
}

// ---------------------------------------------------------------------------
// Scatter-aggregate graph1: agg[dst[e]][d] += x[src[e]][d] * nsrc[src[e]]
// Thread per (edge, dim). 64 consecutive threads share an edge -> coalesced
// 256B row gather, broadcast index loads.
// ---------------------------------------------------------------------------
__global__ void scatter1_kernel(const float* __restrict__ x,
                                const float* __restrict__ nsrc,
                                const int* __restrict__ src,
                                const int* __restrict__ dst,
                                float* __restrict__ agg) {
    unsigned int idx = blockIdx.x * blockDim.x + threadIdx.x;
    unsigned int stride = gridDim.x * blockDim.x;
    const unsigned int total = (unsigned int)cE1 * cD;
    for (; idx < total; idx += stride) {
        unsigned int e = idx >> 6;
        unsigned int d = idx & 63u;
        int s = src[e];
        float v = x[(unsigned int)s * cD + d] * nsrc[s];
        unsafeAtomicAdd(&agg[(unsigned int)dst[e] * cD + d], v);
    }
}

// ---------------------------------------------------------------------------
// Scatter-aggregate graph2. Tiling is virtual: row s of M_feat = hq1[s % N1].
// ---------------------------------------------------------------------------
__global__ void scatter2_kernel(const float* __restrict__ hq1,
                                const float* __restrict__ nsrc,
                                const int* __restrict__ src,
                                const int* __restrict__ dst,
                                float* __restrict__ agg) {
    unsigned int idx = blockIdx.x * blockDim.x + threadIdx.x;
    unsigned int stride = gridDim.x * blockDim.x;
    const unsigned int total = (unsigned int)cE2 * cD;
    for (; idx < total; idx += stride) {
        unsigned int e = idx >> 6;
        unsigned int d = idx & 63u;
        int s = src[e];
        int r = s;                       // s % N1 without integer divide
        if (r >= 2 * cN1) r -= 2 * cN1;
        else if (r >= cN1) r -= cN1;
        float v = hq1[(unsigned int)r * cD + d] * nsrc[s];
        unsafeAtomicAdd(&agg[(unsigned int)dst[e] * cD + d], v);
    }
}

// ---------------------------------------------------------------------------
// Fused: out[row] = leaky( (A[row] * ndst[row]) @ W + b ), 4 rows per block.
// Safe for out == A (in-place): each element is loaded and stored by exactly
// one thread, with __syncthreads() between all loads and all stores.
// ---------------------------------------------------------------------------
__global__ __launch_bounds__(256) void gemm_bias_leaky_kernel(
    const float* __restrict__ A,     // [N,64] aggregated features
    const float* __restrict__ ndst,  // [N] in-degree norm
    const float* __restrict__ W,     // [64,64]
    const float* __restrict__ b,     // [64]
    float* __restrict__ out,         // [N,64] (may alias A)
    int N) {
    __shared__ float Ws[64][64];
    __shared__ float Rs[4][64];
    int tid = threadIdx.x;
    for (int i = tid; i < 64 * 64; i += 256) Ws[i >> 6][i & 63] = W[i];

    int r = tid >> 6;        // 0..3 (= wave id, 64-lane waves)
    int j = tid & 63;        // output column
    int row = blockIdx.x * 4 + r;
    if (row < N) {
        float rn = ndst[row];
        Rs[r][j] = A[(size_t)row * cD + j] * rn;
    }
    __syncthreads();
    if (row < N) {
        float acc = b[j];
#pragma unroll
        for (int k = 0; k < 64; ++k) acc += Rs[r][k] * Ws[k][j];
        acc = acc > 0.0f ? acc : LEAKY * acc;
        out[(size_t)row * cD + j] = acc;
    }
}

extern "C" void kernel_launch(void* const* d_in, const int* in_sizes, int n_in,
                              void* d_out, int out_size, void* d_ws, size_t ws_size,
                              hipStream_t stream) {
    const float* x    = (const float*)d_in[0];
    const float* WQ   = (const float*)d_in[1];
    const float* bQ   = (const float*)d_in[2];
    const float* WM   = (const float*)d_in[3];
    const float* bM   = (const float*)d_in[4];
    const int*   src1 = (const int*)d_in[5];
    const int*   dst1 = (const int*)d_in[6];
    const int*   src2 = (const int*)d_in[7];
    const int*   dst2 = (const int*)d_in[8];
    float* out = (float*)d_out;

    // Workspace layout (floats):
    //   deg_out1[N1] deg_in1[N1] deg_out2[N2] deg_in2[N2] agg1[N1*64] hq1[N1*64]
    float* ws       = (float*)d_ws;
    float* deg_out1 = ws;
    float* deg_in1  = deg_out1 + cN1;
    float* deg_out2 = deg_in1 + cN1;
    float* deg_in2  = deg_out2 + cN2;
    float* agg1     = deg_in2 + cN2;
    float* hq1      = agg1 + (size_t)cN1 * cD;

    const size_t zero_floats = 2 * (size_t)cN1 + 2 * (size_t)cN2 + (size_t)cN1 * cD;
    hipMemsetAsync(ws, 0, zero_floats * sizeof(float), stream);
    hipMemsetAsync(out, 0, (size_t)cN2 * cD * sizeof(float), stream);  // out doubles as agg2

    deg_kernel<<<(cE1 + 255) / 256, 256, 0, stream>>>(src1, dst1, deg_out1, deg_in1, cE1);
    deg_kernel<<<(cE2 + 255) / 256, 256, 0, stream>>>(src2, dst2, deg_out2, deg_in2, cE2);

    const int nNorm = 2 * cN1 + 2 * cN2;
    norm_kernel<<<(nNorm + 255) / 256, 256, 0, stream>>>(ws, nNorm);

    scatter1_kernel<<<8192, 256, 0, stream>>>(x, deg_out1, src1, dst1, agg1);
    gemm_bias_leaky_kernel<<<(cN1 + 3) / 4, 256, 0, stream>>>(agg1, deg_in1, WQ, bQ, hq1, cN1);

    scatter2_kernel<<<8192, 256, 0, stream>>>(hq1, deg_out2, src2, dst2, out);
    gemm_bias_leaky_kernel<<<(cN2 + 3) / 4, 256, 0, stream>>>(out, deg_in2, WM, bM, out, cN2);
}

// Round 2
// 927.315 us; speedup vs baseline: 1.2184x; 1.2184x over previous
//
#include <hip/hip_runtime.h>

// Problem constants (match reference setup_inputs()).
constexpr int cN1 = 50000;
constexpr int cNL = 3;
constexpr int cN2 = cN1 * cNL;   // 150000
constexpr int cE1 = 800000;
constexpr int cE2 = 2400000;
constexpr int cD  = 64;
#define LEAKY 0.01f

// ---------------------------------------------------------------------------
// Int degree counting: cnt_out[src[e]]++, cnt_in[dst[e]]++
// ---------------------------------------------------------------------------
__global__ void deg_int_kernel(const int* __restrict__ src, const int* __restrict__ dst,
                               int* __restrict__ cout_, int* __restrict__ cin_, int E) {
    int i = blockIdx.x * blockDim.x + threadIdx.x;
    int stride = gridDim.x * blockDim.x;
    for (; i < E; i += stride) {
        atomicAdd(&cout_[src[i]], 1);
        atomicAdd(&cin_[dst[i]], 1);
    }
}

// norm[i] = rsqrt(max(cnt[i],1))  (counts block and norms block share layout)
__global__ void norm_from_cnt_kernel(const int* __restrict__ cnt, float* __restrict__ norm, int n) {
    int i = blockIdx.x * blockDim.x + threadIdx.x;
    int stride = gridDim.x * blockDim.x;
    for (; i < n; i += stride) {
        int d = cnt[i];
        d = d < 1 ? 1 : d;
        norm[i] = rsqrtf((float)d);
    }
}

// ---------------------------------------------------------------------------
// 3-kernel exclusive scan (N <= 256*1024 elements)
// ---------------------------------------------------------------------------
constexpr int SCAN_T = 256;
constexpr int SCAN_V = 4;
constexpr int SCAN_B = SCAN_T * SCAN_V;  // 1024 elems per block

__global__ __launch_bounds__(SCAN_T) void scan_partial_kernel(
    const int* __restrict__ cnt, int n, int* __restrict__ bsum) {
    __shared__ int s[SCAN_T];
    int b = blockIdx.x, tid = threadIdx.x;
    int base = b * SCAN_B + tid * SCAN_V;
    int t = 0;
#pragma unroll
    for (int j = 0; j < SCAN_V; ++j) { int i = base + j; if (i < n) t += cnt[i]; }
    s[tid] = t; __syncthreads();
    for (int off = SCAN_T / 2; off > 0; off >>= 1) {
        if (tid < off) s[tid] += s[tid + off];
        __syncthreads();
    }
    if (tid == 0) bsum[b] = s[0];
}

__global__ __launch_bounds__(SCAN_T) void scan_bsum_kernel(int* __restrict__ bsum, int nb) {
    __shared__ int s[SCAN_T];
    int tid = threadIdx.x;
    int v = (tid < nb) ? bsum[tid] : 0;
    s[tid] = v; __syncthreads();
    for (int off = 1; off < SCAN_T; off <<= 1) {
        int a = (tid >= off) ? s[tid - off] : 0;
        __syncthreads();
        s[tid] += a;
        __syncthreads();
    }
    if (tid < nb) bsum[tid] = s[tid] - v;  // exclusive
}

__global__ __launch_bounds__(SCAN_T) void scan_final_kernel(
    const int* __restrict__ cnt, int n, const int* __restrict__ bsum,
    int* __restrict__ offs, int* __restrict__ cur) {
    __shared__ int s[SCAN_T];
    int b = blockIdx.x, tid = threadIdx.x;
    int base = b * SCAN_B + tid * SCAN_V;
    int v[SCAN_V];
    int t = 0;
#pragma unroll
    for (int j = 0; j < SCAN_V; ++j) { int i = base + j; v[j] = (i < n) ? cnt[i] : 0; t += v[j]; }
    s[tid] = t; __syncthreads();
    for (int off = 1; off < SCAN_T; off <<= 1) {
        int a = (tid >= off) ? s[tid - off] : 0;
        __syncthreads();
        s[tid] += a;
        __syncthreads();
    }
    int run = s[tid] - t + bsum[b];
#pragma unroll
    for (int j = 0; j < SCAN_V; ++j) {
        int i = base + j;
        if (i < n) { offs[i] = run; cur[i] = run; run += v[j]; }
    }
}

// ---------------------------------------------------------------------------
// Binning: place src of each edge into its dst's CSR bin.
// ---------------------------------------------------------------------------
__global__ void bin_kernel(const int* __restrict__ src, const int* __restrict__ dst, int E,
                           int* __restrict__ cur, int* __restrict__ sorted_src) {
    int i = blockIdx.x * blockDim.x + threadIdx.x;
    int stride = gridDim.x * blockDim.x;
    for (; i < E; i += stride) {
        int d = dst[i];
        int p = atomicAdd(&cur[d], 1);
        sorted_src[p] = src[i];
    }
}

// ---------------------------------------------------------------------------
// CSR segmented aggregation: one 64-lane wave per dst node, lane = feature dim.
//   agg[w][lane] = sum over incoming edges of feat[fold(src)][lane] * nsrc[src]
// FOLD: src index mod N1 (virtual kron tiling) for layer 2.
// ---------------------------------------------------------------------------
template <bool FOLD>
__global__ __launch_bounds__(256) void agg_csr_kernel(
    const float* __restrict__ feat, const float* __restrict__ nsrc,
    const int* __restrict__ sorted_src, const int* __restrict__ offs,
    const int* __restrict__ ends, float* __restrict__ agg, int N) {
    int w = (blockIdx.x * blockDim.x + threadIdx.x) >> 6;
    int lane = threadIdx.x & 63;
    if (w >= N) return;
    int k0 = offs[w];
    int k1 = ends[w];
    float acc = 0.0f;
    for (int k = k0; k < k1; ++k) {
        int s = sorted_src[k];
        int r = s;
        if (FOLD) {
            if (r >= 2 * cN1) r -= 2 * cN1;
            else if (r >= cN1) r -= cN1;
        }
        acc += feat[(size_t)r * cD + lane] * nsrc[s];
    }
    agg[(size_t)w * cD + lane] = acc;
}

// ---------------------------------------------------------------------------
// Fused: out[row] = leaky( (A[row] * ndst[row]) @ W + b ), 4 rows per block.
// Safe for out == A (each element loaded/stored by exactly one thread with a
// barrier between loads and stores).
// ---------------------------------------------------------------------------
__global__ __launch_bounds__(256) void gemm_bias_leaky_kernel(
    const float* __restrict__ A, const float* __restrict__ ndst,
    const float* __restrict__ W, const float* __restrict__ b,
    float* __restrict__ out, int N) {
    __shared__ float Ws[64][64];
    __shared__ float Rs[4][64];
    int tid = threadIdx.x;
    for (int i = tid; i < 64 * 64; i += 256) Ws[i >> 6][i & 63] = W[i];

    int r = tid >> 6;
    int j = tid & 63;
    int row = blockIdx.x * 4 + r;
    if (row < N) {
        float rn = ndst[row];
        Rs[r][j] = A[(size_t)row * cD + j] * rn;
    }
    __syncthreads();
    if (row < N) {
        float acc = b[j];
#pragma unroll
        for (int k = 0; k < 64; ++k) acc += Rs[r][k] * Ws[k][j];
        acc = acc > 0.0f ? acc : LEAKY * acc;
        out[(size_t)row * cD + j] = acc;
    }
}

extern "C" void kernel_launch(void* const* d_in, const int* in_sizes, int n_in,
                              void* d_out, int out_size, void* d_ws, size_t ws_size,
                              hipStream_t stream) {
    const float* x    = (const float*)d_in[0];
    const float* WQ   = (const float*)d_in[1];
    const float* bQ   = (const float*)d_in[2];
    const float* WM   = (const float*)d_in[3];
    const float* bM   = (const float*)d_in[4];
    const int*   src1 = (const int*)d_in[5];
    const int*   dst1 = (const int*)d_in[6];
    const int*   src2 = (const int*)d_in[7];
    const int*   dst2 = (const int*)d_in[8];
    float* out = (float*)d_out;

    // Workspace layout (all 4-byte words):
    //   cnt_out1[N1] cnt_in1[N1] cnt_out2[N2] cnt_in2[N2]      (ints, zeroed)
    //   nsrc1[N1] ndst1[N1] nsrc2[N2] ndst2[N2]                (floats)
    //   offs1[N1] offs2[N2] cur1[N1] cur2[N2]                  (ints)
    //   bsum[256]                                              (ints)
    //   sorted2[E2]                                            (ints)
    //   aggbuf[N1*64]                                          (floats, = agg1 then hq1)
    char* p = (char*)d_ws;
    int*   cnt_out1 = (int*)p;               p += sizeof(int) * cN1;
    int*   cnt_in1  = (int*)p;               p += sizeof(int) * cN1;
    int*   cnt_out2 = (int*)p;               p += sizeof(int) * cN2;
    int*   cnt_in2  = (int*)p;               p += sizeof(int) * cN2;
    float* nsrc1    = (float*)p;             p += sizeof(float) * cN1;
    float* ndst1    = (float*)p;             p += sizeof(float) * cN1;
    float* nsrc2    = (float*)p;             p += sizeof(float) * cN2;
    float* ndst2    = (float*)p;             p += sizeof(float) * cN2;
    int*   offs1    = (int*)p;               p += sizeof(int) * cN1;
    int*   offs2    = (int*)p;               p += sizeof(int) * cN2;
    int*   cur1     = (int*)p;               p += sizeof(int) * cN1;
    int*   cur2     = (int*)p;               p += sizeof(int) * cN2;
    int*   bsum     = (int*)p;               p += sizeof(int) * 256;
    int*   sorted2  = (int*)p;               p += sizeof(int) * cE2;
    float* aggbuf   = (float*)p;             p += sizeof(float) * (size_t)cN1 * cD;
    // sorted1 lives in the tail of d_out (overwritten later by agg2/gemm2).
    int*   sorted1  = (int*)out + ((size_t)cN2 * cD - cE1);

    const int nCnt = 2 * cN1 + 2 * cN2;  // 400000
    hipMemsetAsync(cnt_out1, 0, sizeof(int) * nCnt, stream);

    // Degrees (int) for both graphs.
    deg_int_kernel<<<2048, 256, 0, stream>>>(src1, dst1, cnt_out1, cnt_in1, cE1);
    deg_int_kernel<<<2048, 256, 0, stream>>>(src2, dst2, cnt_out2, cnt_in2, cE2);

    // Norms: counts block -> norms block, identical layout.
    norm_from_cnt_kernel<<<(nCnt + 255) / 256, 256, 0, stream>>>(cnt_out1, nsrc1, nCnt);

    // ---- Graph 1 CSR ----
    const int nb1 = (cN1 + SCAN_B - 1) / SCAN_B;  // 49
    scan_partial_kernel<<<nb1, SCAN_T, 0, stream>>>(cnt_in1, cN1, bsum);
    scan_bsum_kernel<<<1, SCAN_T, 0, stream>>>(bsum, nb1);
    scan_final_kernel<<<nb1, SCAN_T, 0, stream>>>(cnt_in1, cN1, bsum, offs1, cur1);
    bin_kernel<<<2048, 256, 0, stream>>>(src1, dst1, cE1, cur1, sorted1);
    agg_csr_kernel<false><<<(cN1 + 3) / 4, 256, 0, stream>>>(x, nsrc1, sorted1, offs1, cur1, aggbuf, cN1);
    gemm_bias_leaky_kernel<<<(cN1 + 3) / 4, 256, 0, stream>>>(aggbuf, ndst1, WQ, bQ, aggbuf, cN1);

    // ---- Graph 2 CSR ----
    const int nb2 = (cN2 + SCAN_B - 1) / SCAN_B;  // 147
    scan_partial_kernel<<<nb2, SCAN_T, 0, stream>>>(cnt_in2, cN2, bsum);
    scan_bsum_kernel<<<1, SCAN_T, 0, stream>>>(bsum, nb2);
    scan_final_kernel<<<nb2, SCAN_T, 0, stream>>>(cnt_in2, cN2, bsum, offs2, cur2);
    bin_kernel<<<2048, 256, 0, stream>>>(src2, dst2, cE2, cur2, sorted2);
    agg_csr_kernel<true><<<(cN2 + 3) / 4, 256, 0, stream>>>(aggbuf, nsrc2, sorted2, offs2, cur2, out, cN2);
    gemm_bias_leaky_kernel<<<(cN2 + 3) / 4, 256, 0, stream>>>(out, ndst2, WM, bM, out, cN2);
}

// Round 3
// 684.112 us; speedup vs baseline: 1.6515x; 1.3555x over previous
//
#include <hip/hip_runtime.h>

// Problem constants (match reference setup_inputs()).
constexpr int cN1 = 50000;
constexpr int cNL = 3;
constexpr int cN2 = cN1 * cNL;   // 150000
constexpr int cE1 = 800000;
constexpr int cE2 = 2400000;
constexpr int cD  = 64;
#define LEAKY 0.01f

// ---------------------------------------------------------------------------
// Int degree counting: cnt_out[src[e]]++, cnt_in[dst[e]]++
// ---------------------------------------------------------------------------
__global__ void deg_int_kernel(const int* __restrict__ src, const int* __restrict__ dst,
                               int* __restrict__ cout_, int* __restrict__ cin_, int E) {
    int i = blockIdx.x * blockDim.x + threadIdx.x;
    int stride = gridDim.x * blockDim.x;
    for (; i < E; i += stride) {
        atomicAdd(&cout_[src[i]], 1);
        atomicAdd(&cin_[dst[i]], 1);
    }
}

// norm[i] = rsqrt(max(cnt[i],1))  (counts block and norms block share layout)
__global__ void norm_from_cnt_kernel(const int* __restrict__ cnt, float* __restrict__ norm, int n) {
    int i = blockIdx.x * blockDim.x + threadIdx.x;
    int stride = gridDim.x * blockDim.x;
    for (; i < n; i += stride) {
        int d = cnt[i];
        d = d < 1 ? 1 : d;
        norm[i] = rsqrtf((float)d);
    }
}

// ---------------------------------------------------------------------------
// 3-kernel exclusive scan (N <= 256*1024 elements)
// ---------------------------------------------------------------------------
constexpr int SCAN_T = 256;
constexpr int SCAN_V = 4;
constexpr int SCAN_B = SCAN_T * SCAN_V;  // 1024 elems per block

__global__ __launch_bounds__(SCAN_T) void scan_partial_kernel(
    const int* __restrict__ cnt, int n, int* __restrict__ bsum) {
    __shared__ int s[SCAN_T];
    int b = blockIdx.x, tid = threadIdx.x;
    int base = b * SCAN_B + tid * SCAN_V;
    int t = 0;
#pragma unroll
    for (int j = 0; j < SCAN_V; ++j) { int i = base + j; if (i < n) t += cnt[i]; }
    s[tid] = t; __syncthreads();
    for (int off = SCAN_T / 2; off > 0; off >>= 1) {
        if (tid < off) s[tid] += s[tid + off];
        __syncthreads();
    }
    if (tid == 0) bsum[b] = s[0];
}

__global__ __launch_bounds__(SCAN_T) void scan_bsum_kernel(int* __restrict__ bsum, int nb) {
    __shared__ int s[SCAN_T];
    int tid = threadIdx.x;
    int v = (tid < nb) ? bsum[tid] : 0;
    s[tid] = v; __syncthreads();
    for (int off = 1; off < SCAN_T; off <<= 1) {
        int a = (tid >= off) ? s[tid - off] : 0;
        __syncthreads();
        s[tid] += a;
        __syncthreads();
    }
    if (tid < nb) bsum[tid] = s[tid] - v;  // exclusive
}

__global__ __launch_bounds__(SCAN_T) void scan_final_kernel(
    const int* __restrict__ cnt, int n, const int* __restrict__ bsum,
    int* __restrict__ offs, int* __restrict__ cur) {
    __shared__ int s[SCAN_T];
    int b = blockIdx.x, tid = threadIdx.x;
    int base = b * SCAN_B + tid * SCAN_V;
    int v[SCAN_V];
    int t = 0;
#pragma unroll
    for (int j = 0; j < SCAN_V; ++j) { int i = base + j; v[j] = (i < n) ? cnt[i] : 0; t += v[j]; }
    s[tid] = t; __syncthreads();
    for (int off = 1; off < SCAN_T; off <<= 1) {
        int a = (tid >= off) ? s[tid - off] : 0;
        __syncthreads();
        s[tid] += a;
        __syncthreads();
    }
    int run = s[tid] - t + bsum[b];
#pragma unroll
    for (int j = 0; j < SCAN_V; ++j) {
        int i = base + j;
        if (i < n) { offs[i] = run; cur[i] = run; run += v[j]; }
    }
}

// ---------------------------------------------------------------------------
// Binning: place src of each edge into its dst's CSR bin.
// ---------------------------------------------------------------------------
__global__ void bin_kernel(const int* __restrict__ src, const int* __restrict__ dst, int E,
                           int* __restrict__ cur, int* __restrict__ sorted_src) {
    int i = blockIdx.x * blockDim.x + threadIdx.x;
    int stride = gridDim.x * blockDim.x;
    for (; i < E; i += stride) {
        int d = dst[i];
        int p = atomicAdd(&cur[d], 1);
        sorted_src[p] = src[i];
    }
}

// ---------------------------------------------------------------------------
// CSR segmented aggregation, high-MLP version.
// One 64-lane wave per dst node; 4 edge-slots (16 lanes each) x float4 lanes
// cover the 64-float row; 2x manual unroll -> 8 gathers in flight per wave.
// FOLD: virtual kron tiling (src % N1). EPI: fuse *ndst + bias + leakyReLU
// (valid because row-scaling commutes with the right-matmul, pre-applied).
// ---------------------------------------------------------------------------
template <bool FOLD, bool EPI>
__global__ __launch_bounds__(256) void agg_csr_kernel(
    const float* __restrict__ feat, const float* __restrict__ nsrc,
    const int* __restrict__ sorted_src, const int* __restrict__ offs,
    const int* __restrict__ ends, float* __restrict__ outp,
    const float* __restrict__ ndst, const float* __restrict__ bias, int N) {
    int w = (blockIdx.x * blockDim.x + threadIdx.x) >> 6;
    if (w >= N) return;
    int lane = threadIdx.x & 63;
    int g = lane >> 4;       // edge slot 0..3
    int c = lane & 15;       // float4 column group (cols 4c..4c+3)

    int k0 = offs[w];
    int k1 = ends[w];
    float ax = 0.f, ay = 0.f, az = 0.f, aw = 0.f;

    int k = k0 + g;
    for (; k + 4 < k1; k += 8) {
        int sA = sorted_src[k];
        int sB = sorted_src[k + 4];
        float nA = nsrc[sA];
        float nB = nsrc[sB];
        int rA = sA, rB = sB;
        if (FOLD) {
            if (rA >= 2 * cN1) rA -= 2 * cN1; else if (rA >= cN1) rA -= cN1;
            if (rB >= 2 * cN1) rB -= 2 * cN1; else if (rB >= cN1) rB -= cN1;
        }
        float4 vA = *(const float4*)(feat + (size_t)rA * cD + c * 4);
        float4 vB = *(const float4*)(feat + (size_t)rB * cD + c * 4);
        ax = fmaf(vA.x, nA, ax); ay = fmaf(vA.y, nA, ay);
        az = fmaf(vA.z, nA, az); aw = fmaf(vA.w, nA, aw);
        ax = fmaf(vB.x, nB, ax); ay = fmaf(vB.y, nB, ay);
        az = fmaf(vB.z, nB, az); aw = fmaf(vB.w, nB, aw);
    }
    if (k < k1) {
        int s = sorted_src[k];
        float nv = nsrc[s];
        int r = s;
        if (FOLD) {
            if (r >= 2 * cN1) r -= 2 * cN1; else if (r >= cN1) r -= cN1;
        }
        float4 v = *(const float4*)(feat + (size_t)r * cD + c * 4);
        ax = fmaf(v.x, nv, ax); ay = fmaf(v.y, nv, ay);
        az = fmaf(v.z, nv, az); aw = fmaf(v.w, nv, aw);
    }

    // Butterfly-combine the 4 edge slots (lane bits 4 and 5).
    ax += __shfl_xor(ax, 16); ay += __shfl_xor(ay, 16);
    az += __shfl_xor(az, 16); aw += __shfl_xor(aw, 16);
    ax += __shfl_xor(ax, 32); ay += __shfl_xor(ay, 32);
    az += __shfl_xor(az, 32); aw += __shfl_xor(aw, 32);

    if (g == 0) {
        float4 r;
        if (EPI) {
            float nd = ndst[w];
            float4 bv = *(const float4*)(bias + c * 4);
            r.x = fmaf(ax, nd, bv.x); r.y = fmaf(ay, nd, bv.y);
            r.z = fmaf(az, nd, bv.z); r.w = fmaf(aw, nd, bv.w);
            r.x = r.x > 0.f ? r.x : LEAKY * r.x;
            r.y = r.y > 0.f ? r.y : LEAKY * r.y;
            r.z = r.z > 0.f ? r.z : LEAKY * r.z;
            r.w = r.w > 0.f ? r.w : LEAKY * r.w;
        } else {
            r.x = ax; r.y = ay; r.z = az; r.w = aw;
        }
        *(float4*)(outp + (size_t)w * cD + c * 4) = r;
    }
}

// ---------------------------------------------------------------------------
// Fused layer-1 GEMM + layer-2 pre-transform:
//   h = leaky((A[row]*ndst[row]) @ WQ + bQ);  g[row] = h @ WM
// ---------------------------------------------------------------------------
__global__ __launch_bounds__(256) void gemm12_kernel(
    const float* __restrict__ A, const float* __restrict__ ndst,
    const float* __restrict__ WQ_, const float* __restrict__ bQ_,
    const float* __restrict__ WM_, float* __restrict__ g, int N) {
    __shared__ float W1[64][64];
    __shared__ float W2[64][64];
    __shared__ float Rs[4][64];
    __shared__ float Hs[4][64];
    int tid = threadIdx.x;
    for (int i = tid; i < 64 * 64; i += 256) {
        W1[i >> 6][i & 63] = WQ_[i];
        W2[i >> 6][i & 63] = WM_[i];
    }
    int r = tid >> 6;
    int j = tid & 63;
    int row = blockIdx.x * 4 + r;
    if (row < N) Rs[r][j] = A[(size_t)row * cD + j] * ndst[row];
    __syncthreads();
    if (row < N) {
        float acc = bQ_[j];
#pragma unroll
        for (int k = 0; k < 64; ++k) acc = fmaf(Rs[r][k], W1[k][j], acc);
        acc = acc > 0.f ? acc : LEAKY * acc;
        Hs[r][j] = acc;
    }
    __syncthreads();
    if (row < N) {
        float acc = 0.f;
#pragma unroll
        for (int k = 0; k < 64; ++k) acc = fmaf(Hs[r][k], W2[k][j], acc);
        g[(size_t)row * cD + j] = acc;
    }
}

extern "C" void kernel_launch(void* const* d_in, const int* in_sizes, int n_in,
                              void* d_out, int out_size, void* d_ws, size_t ws_size,
                              hipStream_t stream) {
    const float* x    = (const float*)d_in[0];
    const float* WQ   = (const float*)d_in[1];
    const float* bQ   = (const float*)d_in[2];
    const float* WM   = (const float*)d_in[3];
    const float* bM   = (const float*)d_in[4];
    const int*   src1 = (const int*)d_in[5];
    const int*   dst1 = (const int*)d_in[6];
    const int*   src2 = (const int*)d_in[7];
    const int*   dst2 = (const int*)d_in[8];
    float* out = (float*)d_out;

    // Workspace layout (4-byte words):
    //   cnt_out1[N1] cnt_in1[N1] cnt_out2[N2] cnt_in2[N2]      (ints, zeroed)
    //   nsrc1[N1] ndst1[N1] nsrc2[N2] ndst2[N2]                (floats)
    //   offs1[N1] offs2[N2] cur1[N1] cur2[N2]                  (ints)
    //   bsum[256]                                              (ints)
    //   sorted2[E2]                                            (ints)
    //   aggbuf[N1*64]                                          (floats: agg1, then g)
    char* p = (char*)d_ws;
    int*   cnt_out1 = (int*)p;   p += sizeof(int) * cN1;
    int*   cnt_in1  = (int*)p;   p += sizeof(int) * cN1;
    int*   cnt_out2 = (int*)p;   p += sizeof(int) * cN2;
    int*   cnt_in2  = (int*)p;   p += sizeof(int) * cN2;
    float* nsrc1    = (float*)p; p += sizeof(float) * cN1;
    float* ndst1    = (float*)p; p += sizeof(float) * cN1;
    float* nsrc2    = (float*)p; p += sizeof(float) * cN2;
    float* ndst2    = (float*)p; p += sizeof(float) * cN2;
    int*   offs1    = (int*)p;   p += sizeof(int) * cN1;
    int*   offs2    = (int*)p;   p += sizeof(int) * cN2;
    int*   cur1     = (int*)p;   p += sizeof(int) * cN1;
    int*   cur2     = (int*)p;   p += sizeof(int) * cN2;
    int*   bsum     = (int*)p;   p += sizeof(int) * 256;
    int*   sorted2  = (int*)p;   p += sizeof(int) * cE2;
    float* aggbuf   = (float*)p; p += sizeof(float) * (size_t)cN1 * cD;
    // sorted1 in the tail of d_out (dead before agg2 writes out).
    int*   sorted1  = (int*)out + ((size_t)cN2 * cD - cE1);

    const int nCnt = 2 * cN1 + 2 * cN2;  // 400000
    hipMemsetAsync(cnt_out1, 0, sizeof(int) * nCnt, stream);

    deg_int_kernel<<<2048, 256, 0, stream>>>(src1, dst1, cnt_out1, cnt_in1, cE1);
    deg_int_kernel<<<2048, 256, 0, stream>>>(src2, dst2, cnt_out2, cnt_in2, cE2);
    norm_from_cnt_kernel<<<(nCnt + 255) / 256, 256, 0, stream>>>(cnt_out1, nsrc1, nCnt);

    // ---- Graph 1 ----
    const int nb1 = (cN1 + SCAN_B - 1) / SCAN_B;  // 49
    scan_partial_kernel<<<nb1, SCAN_T, 0, stream>>>(cnt_in1, cN1, bsum);
    scan_bsum_kernel<<<1, SCAN_T, 0, stream>>>(bsum, nb1);
    scan_final_kernel<<<nb1, SCAN_T, 0, stream>>>(cnt_in1, cN1, bsum, offs1, cur1);
    bin_kernel<<<2048, 256, 0, stream>>>(src1, dst1, cE1, cur1, sorted1);
    agg_csr_kernel<false, false><<<(cN1 + 3) / 4, 256, 0, stream>>>(
        x, nsrc1, sorted1, offs1, cur1, aggbuf, nullptr, nullptr, cN1);
    gemm12_kernel<<<(cN1 + 3) / 4, 256, 0, stream>>>(aggbuf, ndst1, WQ, bQ, WM, aggbuf, cN1);

    // ---- Graph 2 ----
    const int nb2 = (cN2 + SCAN_B - 1) / SCAN_B;  // 147
    scan_partial_kernel<<<nb2, SCAN_T, 0, stream>>>(cnt_in2, cN2, bsum);
    scan_bsum_kernel<<<1, SCAN_T, 0, stream>>>(bsum, nb2);
    scan_final_kernel<<<nb2, SCAN_T, 0, stream>>>(cnt_in2, cN2, bsum, offs2, cur2);
    bin_kernel<<<2048, 256, 0, stream>>>(src2, dst2, cE2, cur2, sorted2);
    agg_csr_kernel<true, true><<<(cN2 + 3) / 4, 256, 0, stream>>>(
        aggbuf, nsrc2, sorted2, offs2, cur2, out, ndst2, bM, cN2);
}

// Round 4
// 577.171 us; speedup vs baseline: 1.9575x; 1.1853x over previous
//
#include <hip/hip_runtime.h>

// Problem constants (match reference setup_inputs()).
constexpr int cN1 = 50000;
constexpr int cNL = 3;
constexpr int cN2 = cN1 * cNL;   // 150000
constexpr int cE1 = 800000;
constexpr int cE2 = 2400000;
constexpr int cD  = 64;
#define LEAKY 0.01f

// ---------------------------------------------------------------------------
// Int degree counting: cnt_out[src[e]]++, cnt_in[dst[e]]++
// ---------------------------------------------------------------------------
__global__ void deg_int_kernel(const int* __restrict__ src, const int* __restrict__ dst,
                               int* __restrict__ cout_, int* __restrict__ cin_, int E) {
    int i = blockIdx.x * blockDim.x + threadIdx.x;
    int stride = gridDim.x * blockDim.x;
    for (; i < E; i += stride) {
        atomicAdd(&cout_[src[i]], 1);
        atomicAdd(&cin_[dst[i]], 1);
    }
}

// norm[i] = rsqrt(max(cnt[i],1))  (counts block and norms block share layout)
__global__ void norm_from_cnt_kernel(const int* __restrict__ cnt, float* __restrict__ norm, int n) {
    int i = blockIdx.x * blockDim.x + threadIdx.x;
    int stride = gridDim.x * blockDim.x;
    for (; i < n; i += stride) {
        int d = cnt[i];
        d = d < 1 ? 1 : d;
        norm[i] = rsqrtf((float)d);
    }
}

// ---------------------------------------------------------------------------
// 3-kernel exclusive scan (N <= 256*1024 elements)
// ---------------------------------------------------------------------------
constexpr int SCAN_T = 256;
constexpr int SCAN_V = 4;
constexpr int SCAN_B = SCAN_T * SCAN_V;  // 1024 elems per block

__global__ __launch_bounds__(SCAN_T) void scan_partial_kernel(
    const int* __restrict__ cnt, int n, int* __restrict__ bsum) {
    __shared__ int s[SCAN_T];
    int b = blockIdx.x, tid = threadIdx.x;
    int base = b * SCAN_B + tid * SCAN_V;
    int t = 0;
#pragma unroll
    for (int j = 0; j < SCAN_V; ++j) { int i = base + j; if (i < n) t += cnt[i]; }
    s[tid] = t; __syncthreads();
    for (int off = SCAN_T / 2; off > 0; off >>= 1) {
        if (tid < off) s[tid] += s[tid + off];
        __syncthreads();
    }
    if (tid == 0) bsum[b] = s[0];
}

__global__ __launch_bounds__(SCAN_T) void scan_bsum_kernel(int* __restrict__ bsum, int nb) {
    __shared__ int s[SCAN_T];
    int tid = threadIdx.x;
    int v = (tid < nb) ? bsum[tid] : 0;
    s[tid] = v; __syncthreads();
    for (int off = 1; off < SCAN_T; off <<= 1) {
        int a = (tid >= off) ? s[tid - off] : 0;
        __syncthreads();
        s[tid] += a;
        __syncthreads();
    }
    if (tid < nb) bsum[tid] = s[tid] - v;  // exclusive
}

__global__ __launch_bounds__(SCAN_T) void scan_final_kernel(
    const int* __restrict__ cnt, int n, const int* __restrict__ bsum,
    int* __restrict__ offs, int* __restrict__ cur) {
    __shared__ int s[SCAN_T];
    int b = blockIdx.x, tid = threadIdx.x;
    int base = b * SCAN_B + tid * SCAN_V;
    int v[SCAN_V];
    int t = 0;
#pragma unroll
    for (int j = 0; j < SCAN_V; ++j) { int i = base + j; v[j] = (i < n) ? cnt[i] : 0; t += v[j]; }
    s[tid] = t; __syncthreads();
    for (int off = 1; off < SCAN_T; off <<= 1) {
        int a = (tid >= off) ? s[tid - off] : 0;
        __syncthreads();
        s[tid] += a;
        __syncthreads();
    }
    int run = s[tid] - t + bsum[b];
#pragma unroll
    for (int j = 0; j < SCAN_V; ++j) {
        int i = base + j;
        if (i < n) { offs[i] = run; cur[i] = run; run += v[j]; }
    }
}

// ---------------------------------------------------------------------------
// XCD-partitioned binning. Partition p = blockIdx & 7 handles dst range
// [p*npp, (p+1)*npp). Each partition group streams the full edge list
// (sequential reads at full BW) and only bins its own range, so all writers
// of any sorted[] cache line live on one XCD -> L2 merges partial lines and
// the 16x write amplification of naive scatter disappears.
// ---------------------------------------------------------------------------
__global__ __launch_bounds__(256) void bin_part_kernel(
    const int* __restrict__ src, const int* __restrict__ dst, int E,
    int* __restrict__ cur, int* __restrict__ sorted_src, int npp) {
    int p = blockIdx.x & 7;
    int bid = blockIdx.x >> 3;
    int nb = gridDim.x >> 3;
    int lo = p * npp;
    int hi = lo + npp;
    int i = bid * blockDim.x + threadIdx.x;
    int stride = nb * blockDim.x;
    for (; i < E; i += stride) {
        int d = dst[i];
        if (d >= lo && d < hi) {
            int pos = atomicAdd(&cur[d], 1);
            sorted_src[pos] = src[i];
        }
    }
}

// ---------------------------------------------------------------------------
// CSR segmented aggregation, high-MLP version.
// One 64-lane wave per dst node; 4 edge-slots (16 lanes each) x float4 lanes
// cover the 64-float row; 2x manual unroll -> 8 gathers in flight per wave.
// FOLD: virtual kron tiling (src % N1). EPI: fuse *ndst + bias + leakyReLU
// (valid because row-scaling commutes with the right-matmul, pre-applied).
// ---------------------------------------------------------------------------
template <bool FOLD, bool EPI>
__global__ __launch_bounds__(256) void agg_csr_kernel(
    const float* __restrict__ feat, const float* __restrict__ nsrc,
    const int* __restrict__ sorted_src, const int* __restrict__ offs,
    const int* __restrict__ ends, float* __restrict__ outp,
    const float* __restrict__ ndst, const float* __restrict__ bias, int N) {
    int w = (blockIdx.x * blockDim.x + threadIdx.x) >> 6;
    if (w >= N) return;
    int lane = threadIdx.x & 63;
    int g = lane >> 4;       // edge slot 0..3
    int c = lane & 15;       // float4 column group (cols 4c..4c+3)

    int k0 = offs[w];
    int k1 = ends[w];
    float ax = 0.f, ay = 0.f, az = 0.f, aw = 0.f;

    int k = k0 + g;
    for (; k + 4 < k1; k += 8) {
        int sA = sorted_src[k];
        int sB = sorted_src[k + 4];
        float nA = nsrc[sA];
        float nB = nsrc[sB];
        int rA = sA, rB = sB;
        if (FOLD) {
            if (rA >= 2 * cN1) rA -= 2 * cN1; else if (rA >= cN1) rA -= cN1;
            if (rB >= 2 * cN1) rB -= 2 * cN1; else if (rB >= cN1) rB -= cN1;
        }
        float4 vA = *(const float4*)(feat + (size_t)rA * cD + c * 4);
        float4 vB = *(const float4*)(feat + (size_t)rB * cD + c * 4);
        ax = fmaf(vA.x, nA, ax); ay = fmaf(vA.y, nA, ay);
        az = fmaf(vA.z, nA, az); aw = fmaf(vA.w, nA, aw);
        ax = fmaf(vB.x, nB, ax); ay = fmaf(vB.y, nB, ay);
        az = fmaf(vB.z, nB, az); aw = fmaf(vB.w, nB, aw);
    }
    if (k < k1) {
        int s = sorted_src[k];
        float nv = nsrc[s];
        int r = s;
        if (FOLD) {
            if (r >= 2 * cN1) r -= 2 * cN1; else if (r >= cN1) r -= cN1;
        }
        float4 v = *(const float4*)(feat + (size_t)r * cD + c * 4);
        ax = fmaf(v.x, nv, ax); ay = fmaf(v.y, nv, ay);
        az = fmaf(v.z, nv, az); aw = fmaf(v.w, nv, aw);
    }

    // Butterfly-combine the 4 edge slots (lane bits 4 and 5).
    ax += __shfl_xor(ax, 16); ay += __shfl_xor(ay, 16);
    az += __shfl_xor(az, 16); aw += __shfl_xor(aw, 16);
    ax += __shfl_xor(ax, 32); ay += __shfl_xor(ay, 32);
    az += __shfl_xor(az, 32); aw += __shfl_xor(aw, 32);

    if (g == 0) {
        float4 r;
        if (EPI) {
            float nd = ndst[w];
            float4 bv = *(const float4*)(bias + c * 4);
            r.x = fmaf(ax, nd, bv.x); r.y = fmaf(ay, nd, bv.y);
            r.z = fmaf(az, nd, bv.z); r.w = fmaf(aw, nd, bv.w);
            r.x = r.x > 0.f ? r.x : LEAKY * r.x;
            r.y = r.y > 0.f ? r.y : LEAKY * r.y;
            r.z = r.z > 0.f ? r.z : LEAKY * r.z;
            r.w = r.w > 0.f ? r.w : LEAKY * r.w;
        } else {
            r.x = ax; r.y = ay; r.z = az; r.w = aw;
        }
        *(float4*)(outp + (size_t)w * cD + c * 4) = r;
    }
}

// ---------------------------------------------------------------------------
// Fused layer-1 GEMM + layer-2 pre-transform:
//   h = leaky((A[row]*ndst[row]) @ WQ + bQ);  g[row] = h @ WM
// ---------------------------------------------------------------------------
__global__ __launch_bounds__(256) void gemm12_kernel(
    const float* __restrict__ A, const float* __restrict__ ndst,
    const float* __restrict__ WQ_, const float* __restrict__ bQ_,
    const float* __restrict__ WM_, float* __restrict__ g, int N) {
    __shared__ float W1[64][64];
    __shared__ float W2[64][64];
    __shared__ float Rs[4][64];
    __shared__ float Hs[4][64];
    int tid = threadIdx.x;
    for (int i = tid; i < 64 * 64; i += 256) {
        W1[i >> 6][i & 63] = WQ_[i];
        W2[i >> 6][i & 63] = WM_[i];
    }
    int r = tid >> 6;
    int j = tid & 63;
    int row = blockIdx.x * 4 + r;
    if (row < N) Rs[r][j] = A[(size_t)row * cD + j] * ndst[row];
    __syncthreads();
    if (row < N) {
        float acc = bQ_[j];
#pragma unroll
        for (int k = 0; k < 64; ++k) acc = fmaf(Rs[r][k], W1[k][j], acc);
        acc = acc > 0.f ? acc : LEAKY * acc;
        Hs[r][j] = acc;
    }
    __syncthreads();
    if (row < N) {
        float acc = 0.f;
#pragma unroll
        for (int k = 0; k < 64; ++k) acc = fmaf(Hs[r][k], W2[k][j], acc);
        g[(size_t)row * cD + j] = acc;
    }
}

extern "C" void kernel_launch(void* const* d_in, const int* in_sizes, int n_in,
                              void* d_out, int out_size, void* d_ws, size_t ws_size,
                              hipStream_t stream) {
    const float* x    = (const float*)d_in[0];
    const float* WQ   = (const float*)d_in[1];
    const float* bQ   = (const float*)d_in[2];
    const float* WM   = (const float*)d_in[3];
    const float* bM   = (const float*)d_in[4];
    const int*   src1 = (const int*)d_in[5];
    const int*   dst1 = (const int*)d_in[6];
    const int*   src2 = (const int*)d_in[7];
    const int*   dst2 = (const int*)d_in[8];
    float* out = (float*)d_out;

    // Workspace layout (4-byte words):
    //   cnt_out1[N1] cnt_in1[N1] cnt_out2[N2] cnt_in2[N2]      (ints, zeroed)
    //   nsrc1[N1] ndst1[N1] nsrc2[N2] ndst2[N2]                (floats)
    //   offs1[N1] offs2[N2] cur1[N1] cur2[N2]                  (ints)
    //   bsum[256]                                              (ints)
    //   sorted2[E2]                                            (ints)
    //   aggbuf[N1*64]                                          (floats: agg1, then g)
    char* p = (char*)d_ws;
    int*   cnt_out1 = (int*)p;   p += sizeof(int) * cN1;
    int*   cnt_in1  = (int*)p;   p += sizeof(int) * cN1;
    int*   cnt_out2 = (int*)p;   p += sizeof(int) * cN2;
    int*   cnt_in2  = (int*)p;   p += sizeof(int) * cN2;
    float* nsrc1    = (float*)p; p += sizeof(float) * cN1;
    float* ndst1    = (float*)p; p += sizeof(float) * cN1;
    float* nsrc2    = (float*)p; p += sizeof(float) * cN2;
    float* ndst2    = (float*)p; p += sizeof(float) * cN2;
    int*   offs1    = (int*)p;   p += sizeof(int) * cN1;
    int*   offs2    = (int*)p;   p += sizeof(int) * cN2;
    int*   cur1     = (int*)p;   p += sizeof(int) * cN1;
    int*   cur2     = (int*)p;   p += sizeof(int) * cN2;
    int*   bsum     = (int*)p;   p += sizeof(int) * 256;
    int*   sorted2  = (int*)p;   p += sizeof(int) * cE2;
    float* aggbuf   = (float*)p; p += sizeof(float) * (size_t)cN1 * cD;
    // sorted1 in the tail of d_out (dead before agg2 writes out).
    int*   sorted1  = (int*)out + ((size_t)cN2 * cD - cE1);

    const int nCnt = 2 * cN1 + 2 * cN2;  // 400000
    hipMemsetAsync(cnt_out1, 0, sizeof(int) * nCnt, stream);

    deg_int_kernel<<<2048, 256, 0, stream>>>(src1, dst1, cnt_out1, cnt_in1, cE1);
    deg_int_kernel<<<2048, 256, 0, stream>>>(src2, dst2, cnt_out2, cnt_in2, cE2);
    norm_from_cnt_kernel<<<(nCnt + 255) / 256, 256, 0, stream>>>(cnt_out1, nsrc1, nCnt);

    // ---- Graph 1 ----
    const int nb1 = (cN1 + SCAN_B - 1) / SCAN_B;  // 49
    scan_partial_kernel<<<nb1, SCAN_T, 0, stream>>>(cnt_in1, cN1, bsum);
    scan_bsum_kernel<<<1, SCAN_T, 0, stream>>>(bsum, nb1);
    scan_final_kernel<<<nb1, SCAN_T, 0, stream>>>(cnt_in1, cN1, bsum, offs1, cur1);
    bin_part_kernel<<<2048, 256, 0, stream>>>(src1, dst1, cE1, cur1, sorted1, cN1 / 8);
    agg_csr_kernel<false, false><<<(cN1 + 3) / 4, 256, 0, stream>>>(
        x, nsrc1, sorted1, offs1, cur1, aggbuf, nullptr, nullptr, cN1);
    gemm12_kernel<<<(cN1 + 3) / 4, 256, 0, stream>>>(aggbuf, ndst1, WQ, bQ, WM, aggbuf, cN1);

    // ---- Graph 2 ----
    const int nb2 = (cN2 + SCAN_B - 1) / SCAN_B;  // 147
    scan_partial_kernel<<<nb2, SCAN_T, 0, stream>>>(cnt_in2, cN2, bsum);
    scan_bsum_kernel<<<1, SCAN_T, 0, stream>>>(bsum, nb2);
    scan_final_kernel<<<nb2, SCAN_T, 0, stream>>>(cnt_in2, cN2, bsum, offs2, cur2);
    bin_part_kernel<<<2048, 256, 0, stream>>>(src2, dst2, cE2, cur2, sorted2, cN2 / 8);
    agg_csr_kernel<true, true><<<(cN2 + 3) / 4, 256, 0, stream>>>(
        aggbuf, nsrc2, sorted2, offs2, cur2, out, ndst2, bM, cN2);
}